// Round 1
// baseline (1475.722 us; speedup 1.0000x reference)
//
#include <hip/hip_runtime.h>

#define N_NODES 50000
#define N_EDGES 1250000
#define HID 64
#define CDIM 128  // 2*HID

// ---------------------------------------------------------------------------
// Kernel 1: combined[:, 0:64] = x ; combined[:, 64:128] = 0
// combined lives in d_out right after `out`. float4 throughout.
// ---------------------------------------------------------------------------
__global__ __launch_bounds__(256) void k_init(const float4* __restrict__ x4,
                                              float4* __restrict__ comb4) {
  int i = blockIdx.x * blockDim.x + threadIdx.x;  // over N_NODES*32 float4s
  if (i >= N_NODES * 32) return;
  int n = i >> 5;
  int c = i & 31;
  float4 v;
  if (c < 16) {
    v = x4[n * 16 + c];
  } else {
    v = make_float4(0.f, 0.f, 0.f, 0.f);
  }
  comb4[i] = v;
}

// ---------------------------------------------------------------------------
// Kernel 2: scatter-add edge_attr rows into combined[:, 64:128]
// One thread per (edge, float4-quad): coalesced float4 read, 4 f32 atomics.
// ---------------------------------------------------------------------------
__global__ __launch_bounds__(256) void k_scatter(const float4* __restrict__ ea4,
                                                 const int* __restrict__ row,
                                                 float* __restrict__ comb) {
  int i = blockIdx.x * blockDim.x + threadIdx.x;  // over N_EDGES*16
  if (i >= N_EDGES * 16) return;
  int e = i >> 4;
  int q = i & 15;
  float4 v = ea4[i];
  int r = row[e];
  float* dst = comb + (size_t)r * CDIM + HID + q * 4;
  atomicAdd(dst + 0, v.x);
  atomicAdd(dst + 1, v.y);
  atomicAdd(dst + 2, v.z);
  atomicAdd(dst + 3, v.w);
}

// ---------------------------------------------------------------------------
// Kernel 3: MLP. One wave (64 threads) per 64-node tile; lane = node.
//   acc[j]  = b1[j] + sum_k combined[n][k] * W1[k][j]   (k=0..127)
//   h       = silu(acc)
//   acc2[j] = b2[j] + sum_k h[k] * W2[k][j]             (k=0..63)
// Weights indexed uniformly -> scalar s_loads (SGPR broadcast).
// combined rows staged via LDS with XOR swizzle (conflict-free b128).
// h stashed to LDS (rotate swizzle) to allow runtime-k reads without
// spilling a runtime-indexed register array to scratch.
// Output transposed through LDS -> fully coalesced float4 stores.
// ---------------------------------------------------------------------------
__global__ __launch_bounds__(64) void k_mlp(const float* __restrict__ comb,
                                            const float* __restrict__ W1,
                                            const float* __restrict__ b1,
                                            const float* __restrict__ W2,
                                            const float* __restrict__ b2,
                                            float* __restrict__ out) {
  __shared__ float4 lds4[1024];  // 16 KB, reused: A-tile / h-buffer / out-tile
  float* ldsf = (float*)lds4;

  const int l = threadIdx.x;       // lane 0..63
  const int base = blockIdx.x * 64;

  // ---- phase 1: acc[j] = b1[j] + combined_row . W1[:,j] ----
  float acc[HID];
#pragma unroll
  for (int j = 0; j < HID; j++) acc[j] = b1[j];  // uniform -> s_load

  for (int kt = 0; kt < 4; ++kt) {  // k-tiles of 32 over CDIM=128
    // stage 64 nodes x 32 floats (512 float4), coalesced reads, swizzled LDS
#pragma unroll
    for (int s = 0; s < 8; s++) {
      int w = s * 64 + l;          // 0..511
      int r = w >> 3;              // node row in tile
      int c = w & 7;               // float4 chunk within k-tile
      int nn = base + r;
      if (nn >= N_NODES) nn = N_NODES - 1;  // clamp (stores are guarded)
      float4 v = *(const float4*)(comb + (size_t)nn * CDIM + kt * 32 + c * 4);
      lds4[r * 8 + (c ^ (r & 7))] = v;
    }
    __syncthreads();

    const float* w1p = W1 + kt * 32 * HID;
#pragma unroll
    for (int c = 0; c < 8; c++) {  // 4 k-values per iteration
      float4 av = lds4[l * 8 + (c ^ (l & 7))];
      const float* wr = w1p + c * 4 * HID;
#pragma unroll
      for (int j = 0; j < HID; j++) acc[j] = fmaf(av.x, wr[j], acc[j]);
#pragma unroll
      for (int j = 0; j < HID; j++) acc[j] = fmaf(av.y, wr[HID + j], acc[j]);
#pragma unroll
      for (int j = 0; j < HID; j++) acc[j] = fmaf(av.z, wr[2 * HID + j], acc[j]);
#pragma unroll
      for (int j = 0; j < HID; j++) acc[j] = fmaf(av.w, wr[3 * HID + j], acc[j]);
    }
    __syncthreads();  // before next kt overwrites the staging buffer
  }

  // ---- silu ----
#pragma unroll
  for (int j = 0; j < HID; j++) {
    float v = acc[j];
    acc[j] = v / (1.0f + __expf(-v));
  }

  // ---- stash h to LDS (per-lane row, rotate swizzle: 2-way max = free) ----
#pragma unroll
  for (int j = 0; j < HID; j++) ldsf[l * 64 + ((j + l) & 63)] = acc[j];
  // same-lane write->read, single wave: DS ops are in-order; no barrier needed,
  // but keep one for compiler-alias safety (1-wave block: near-free).
  __syncthreads();

  // ---- phase 2: acc2[j] = b2[j] + h . W2[:,j] ----
  float acc2[HID];
#pragma unroll
  for (int j = 0; j < HID; j++) acc2[j] = b2[j];

  for (int k = 0; k < HID; k++) {  // rolled: h[k] via LDS (runtime k)
    float hv = ldsf[l * 64 + ((k + l) & 63)];
    const float* wr = W2 + k * HID;
#pragma unroll
    for (int j = 0; j < HID; j++) acc2[j] = fmaf(hv, wr[j], acc2[j]);
  }
  __syncthreads();  // hbuf dead; about to reuse LDS as out-tile

  // ---- transpose through LDS, coalesced store ----
#pragma unroll
  for (int c = 0; c < 16; c++) {
    float4 v = make_float4(acc2[c * 4], acc2[c * 4 + 1], acc2[c * 4 + 2],
                           acc2[c * 4 + 3]);
    lds4[l * 16 + (c ^ (l & 7))] = v;
  }
  __syncthreads();
#pragma unroll
  for (int s = 0; s < 16; s++) {
    int w = s * 64 + l;
    int r = w >> 4;
    int c = w & 15;
    int nn = base + r;
    if (nn < N_NODES) {
      float4 v = lds4[r * 16 + (c ^ (r & 7))];
      *(float4*)(out + (size_t)nn * HID + c * 4) = v;
    }
  }
}

// ---------------------------------------------------------------------------
extern "C" void kernel_launch(void* const* d_in, const int* in_sizes, int n_in,
                              void* d_out, int out_size, void* d_ws,
                              size_t ws_size, hipStream_t stream) {
  const int* edge_index = (const int*)d_in[0];    // [2][N_EDGES]; row = first half
  const float* edge_attr = (const float*)d_in[1]; // [N_EDGES][64]
  const float* x = (const float*)d_in[2];         // [N_NODES][64]
  const float* W1 = (const float*)d_in[3];        // [128][64]
  const float* b1 = (const float*)d_in[4];        // [64]
  const float* W2 = (const float*)d_in[5];        // [64][64]
  const float* b2 = (const float*)d_in[6];        // [64]

  float* out = (float*)d_out;                       // [N_NODES][64]
  float* comb = out + (size_t)N_NODES * HID;        // [N_NODES][128]

  // 1) combined = [x | 0]
  {
    int total = N_NODES * 32;  // float4s
    k_init<<<(total + 255) / 256, 256, 0, stream>>>((const float4*)x,
                                                    (float4*)comb);
  }
  // 2) scatter-add edges into combined[:, 64:]
  {
    int total = N_EDGES * 16;  // (edge, quad) pairs
    k_scatter<<<(total + 255) / 256, 256, 0, stream>>>((const float4*)edge_attr,
                                                       edge_index, comb);
  }
  // 3) MLP -> out
  {
    int tiles = (N_NODES + 63) / 64;  // 782
    k_mlp<<<tiles, 64, 0, stream>>>(comb, W1, b1, W2, b2, out);
  }
}

// Round 3
// 863.016 us; speedup vs baseline: 1.7100x; 1.7100x over previous
//
#include <hip/hip_runtime.h>

#define N_NODES 50000
#define N_EDGES 1250000
#define HID 64
#define CDIM 128  // 2*HID

// d_ws layout (ints):
//   count  @ 0          [50000]
//   off    @ 50000      [50001]
//   cursor @ 100001     [50000]
//   perm   @ 150001     [1250000]
// total 1,400,001 ints = 5,600,004 bytes
#define WS_NEEDED_BYTES 5600004ull

// ===========================================================================
// Binning path (preferred)
// ===========================================================================

__global__ __launch_bounds__(256) void k_zero(int* __restrict__ count) {
  int i = blockIdx.x * blockDim.x + threadIdx.x;
  if (i < N_NODES) count[i] = 0;
}

// histogram of destination nodes (int atomics, 1.25M ops)
__global__ __launch_bounds__(256) void k_count(const int* __restrict__ row,
                                               int* __restrict__ count) {
  int e = blockIdx.x * blockDim.x + threadIdx.x;
  if (e >= N_EDGES) return;
  atomicAdd(&count[row[e]], 1);
}

// exclusive scan of 50000 counts -> off[50001], cursor[50000]
// single block, 1024 threads, 49 elems/thread + Hillis-Steele over partials
#define CHUNK 49  // 1024*49 = 50176 >= 50000
__global__ __launch_bounds__(1024) void k_scan(const int* __restrict__ count,
                                               int* __restrict__ off,
                                               int* __restrict__ cursor) {
  __shared__ int ps[1024];
  const int t = threadIdx.x;
  const int base = t * CHUNK;
  int s = 0;
  for (int i = 0; i < CHUNK; i++) {
    int idx = base + i;
    if (idx < N_NODES) s += count[idx];
  }
  ps[t] = s;
  __syncthreads();
  for (int d = 1; d < 1024; d <<= 1) {
    int v = (t >= d) ? ps[t - d] : 0;
    __syncthreads();
    ps[t] += v;
    __syncthreads();
  }
  int run = ps[t] - s;  // exclusive prefix for this thread's chunk
  for (int i = 0; i < CHUNK; i++) {
    int idx = base + i;
    if (idx < N_NODES) {
      off[idx] = run;
      cursor[idx] = run;
      run += count[idx];
    }
  }
  if (t == 1023) off[N_NODES] = ps[1023];  // total = N_EDGES
}

// fill permutation: perm[pos] = edge id, pos claimed per-node via int atomic
__global__ __launch_bounds__(256) void k_fill(const int* __restrict__ row,
                                              int* __restrict__ cursor,
                                              int* __restrict__ perm) {
  int e = blockIdx.x * blockDim.x + threadIdx.x;
  if (e >= N_EDGES) return;
  int pos = atomicAdd(&cursor[row[e]], 1);
  perm[pos] = e;
}

// gather-sum per node + build combined = [x | agg]
// one wave per node; lane = feature column; edge row = one 256B coalesced load
__global__ __launch_bounds__(256) void k_gather(const float* __restrict__ ea,
                                                const float* __restrict__ x,
                                                const int* __restrict__ off,
                                                const int* __restrict__ perm,
                                                float* __restrict__ comb) {
  const int wid = threadIdx.x >> 6;
  const int l = threadIdx.x & 63;
  const int n = blockIdx.x * 4 + wid;  // 12500*4 == 50000 exactly
  // uniform range -> SGPR so perm[i] becomes scalar loads
  int s = __builtin_amdgcn_readfirstlane(off[n]);
  int e0 = __builtin_amdgcn_readfirstlane(off[n + 1]);
  float acc = 0.f;
  int i = s;
  for (; i + 1 < e0; i += 2) {  // two independent row reads in flight
    int e1 = perm[i];
    int e2 = perm[i + 1];
    float v1 = ea[(size_t)e1 * HID + l];
    float v2 = ea[(size_t)e2 * HID + l];
    acc += v1;
    acc += v2;
  }
  if (i < e0) acc += ea[(size_t)perm[i] * HID + l];
  comb[(size_t)n * CDIM + l] = x[(size_t)n * HID + l];
  comb[(size_t)n * CDIM + HID + l] = acc;
}

// ===========================================================================
// Fallback path (round-1, known-passing): init + f32-atomic scatter
// ===========================================================================

__global__ __launch_bounds__(256) void k_init(const float4* __restrict__ x4,
                                              float4* __restrict__ comb4) {
  int i = blockIdx.x * blockDim.x + threadIdx.x;  // over N_NODES*32 float4s
  if (i >= N_NODES * 32) return;
  int n = i >> 5;
  int c = i & 31;
  float4 v;
  if (c < 16) {
    v = x4[n * 16 + c];
  } else {
    v = make_float4(0.f, 0.f, 0.f, 0.f);
  }
  comb4[i] = v;
}

__global__ __launch_bounds__(256) void k_scatter(const float4* __restrict__ ea4,
                                                 const int* __restrict__ row,
                                                 float* __restrict__ comb) {
  int i = blockIdx.x * blockDim.x + threadIdx.x;  // over N_EDGES*16
  if (i >= N_EDGES * 16) return;
  int e = i >> 4;
  int q = i & 15;
  float4 v = ea4[i];
  int r = row[e];
  float* dst = comb + (size_t)r * CDIM + HID + q * 4;
  atomicAdd(dst + 0, v.x);
  atomicAdd(dst + 1, v.y);
  atomicAdd(dst + 2, v.z);
  atomicAdd(dst + 3, v.w);
}

// ===========================================================================
// MLP: thread = (node, output j). 4 nodes per 256-thread block.
// ===========================================================================
__global__ __launch_bounds__(256) void k_mlp(const float* __restrict__ comb,
                                             const float* __restrict__ W1,
                                             const float* __restrict__ b1,
                                             const float* __restrict__ W2,
                                             const float* __restrict__ b2,
                                             float* __restrict__ out) {
  __shared__ float hbuf[4][HID];
  const int j = threadIdx.x & 63;
  const int nl = threadIdx.x >> 6;
  const int n = blockIdx.x * 4 + nl;  // 12500*4 == 50000 exactly

  const float4* c4 = (const float4*)(comb + (size_t)n * CDIM);
  float acc = b1[j];
#pragma unroll 4
  for (int k4 = 0; k4 < 32; ++k4) {
    float4 c = c4[k4];
    const float* w = W1 + (size_t)(k4 * 4) * HID + j;
    acc = fmaf(c.x, w[0 * HID], acc);
    acc = fmaf(c.y, w[1 * HID], acc);
    acc = fmaf(c.z, w[2 * HID], acc);
    acc = fmaf(c.w, w[3 * HID], acc);
  }
  // silu
  float h = acc / (1.0f + expf(-acc));
  hbuf[nl][j] = h;
  __syncthreads();

  float acc2 = b2[j];
#pragma unroll 8
  for (int k = 0; k < HID; ++k) {
    acc2 = fmaf(hbuf[nl][k], W2[(size_t)k * HID + j], acc2);
  }
  out[(size_t)n * HID + j] = acc2;
}

// ===========================================================================
extern "C" void kernel_launch(void* const* d_in, const int* in_sizes, int n_in,
                              void* d_out, int out_size, void* d_ws,
                              size_t ws_size, hipStream_t stream) {
  const int* edge_index = (const int*)d_in[0];    // [2][N_EDGES]; row = first half
  const float* edge_attr = (const float*)d_in[1]; // [N_EDGES][64]
  const float* x = (const float*)d_in[2];         // [N_NODES][64]
  const float* W1 = (const float*)d_in[3];        // [128][64]
  const float* b1 = (const float*)d_in[4];        // [64]
  const float* W2 = (const float*)d_in[5];        // [64][64]
  const float* b2 = (const float*)d_in[6];        // [64]

  float* out = (float*)d_out;                  // [N_NODES][64]
  float* comb = out + (size_t)N_NODES * HID;   // [N_NODES][128]

  if (ws_size >= WS_NEEDED_BYTES) {
    // ---- binning path: zero f32 atomics ----
    int* ws = (int*)d_ws;
    int* count = ws;            // [50000]
    int* off = ws + 50000;      // [50001]
    int* cursor = ws + 100001;  // [50000]
    int* perm = ws + 150001;    // [1250000]

    k_zero<<<(N_NODES + 255) / 256, 256, 0, stream>>>(count);
    k_count<<<(N_EDGES + 255) / 256, 256, 0, stream>>>(edge_index, count);
    k_scan<<<1, 1024, 0, stream>>>(count, off, cursor);
    k_fill<<<(N_EDGES + 255) / 256, 256, 0, stream>>>(edge_index, cursor, perm);
    k_gather<<<N_NODES / 4, 256, 0, stream>>>(edge_attr, x, off, perm, comb);
  } else {
    // ---- fallback: f32-atomic scatter (round-1 behavior) ----
    k_init<<<(N_NODES * 32 + 255) / 256, 256, 0, stream>>>((const float4*)x,
                                                           (float4*)comb);
    k_scatter<<<(N_EDGES * 16 + 255) / 256, 256, 0, stream>>>(
        (const float4*)edge_attr, edge_index, comb);
  }

  k_mlp<<<N_NODES / 4, 256, 0, stream>>>(comb, W1, b1, W2, b2, out);
}